// Round 2
// baseline (2755.675 us; speedup 1.0000x reference)
//
#include <hip/hip_runtime.h>
#include <math.h>

#define B_ 8
#define N_ 2048
#define D_ 128
#define E_ 256
#define K_ 16
#define LN_EPS 1e-5f

// ---------------------------------------------------------------------------
// Reference-matching f32 distance: d2 = (sq_n + sq_m) - 2*dot, each op rounded
// f32, NO FMA contraction (numpy einsum uses explicit mul+add SSE, and the
// expanded form's ~1e-6 abs rounding error determines the top-16 set at
// near-tie boundaries -- we must reproduce it, not improve on it).
// ---------------------------------------------------------------------------
__device__ __forceinline__ float sq3_ref(float x, float y, float z) {
#pragma clang fp contract(off)
    float s = x * x + y * y;
    s = s + z * z;
    return s;
}

__device__ __forceinline__ float d2_ref(float qx, float qy, float qz, float sqq,
                                        float mx, float my, float mz, float sqm) {
#pragma clang fp contract(off)
    float dot = mx * qx + my * qy;
    dot = dot + mz * qz;
    float t1 = sqq + sqm;
    float t2 = 2.0f * dot;
    float d2 = t1 - t2;
    return d2 > 0.0f ? d2 : 0.0f;
}

// ---------------------------------------------------------------------------
// Kernel 1: kNN top-16 per point, bitwise-matching the reference's f32
// expanded-form distances. One thread = one query; coords staged in LDS.
// Stable tie-break (lower index wins) matches stable argsort / lax.top_k.
// ---------------------------------------------------------------------------
__global__ __launch_bounds__(64) void knn_topk_kernel(const float* __restrict__ coords,
                                                      int* __restrict__ knn_out) {
    __shared__ float lc[3][N_];
    __shared__ float lsq[N_];
    const int b  = blockIdx.x >> 5;   // 2048/64 = 32 blocks per batch
    const int nb = blockIdx.x & 31;
    const int t  = threadIdx.x;
    const float* cb = coords + (size_t)b * N_ * 3;
    for (int i = t; i < N_ * 3; i += 64) {
        int n = i / 3;
        int c = i - 3 * n;
        lc[c][n] = cb[i];
    }
    __syncthreads();
    for (int n = t; n < N_; n += 64) lsq[n] = sq3_ref(lc[0][n], lc[1][n], lc[2][n]);
    __syncthreads();

    const int n0 = nb * 64 + t;
    const float qx = lc[0][n0], qy = lc[1][n0], qz = lc[2][n0];
    const float sqq = lsq[n0];

    float bd[K_];
    int   bi[K_];
#pragma unroll
    for (int j = 0; j < K_; ++j) { bd[j] = 3.402823e38f; bi[j] = 0; }

    for (int m = 0; m < N_; ++m) {
        const float d2 = d2_ref(qx, qy, qz, sqq, lc[0][m], lc[1][m], lc[2][m], lsq[m]);
        if (d2 < bd[K_ - 1]) {           // strict <: ties keep incumbent (lower idx)
#pragma unroll
            for (int j = K_ - 1; j >= 1; --j) {
                const bool  sh  = d2 < bd[j - 1];
                const bool  ins = d2 < bd[j];
                const float nbv = sh ? bd[j - 1] : (ins ? d2 : bd[j]);
                const int   niv = sh ? bi[j - 1] : (ins ? m  : bi[j]);
                bd[j] = nbv; bi[j] = niv;
            }
            if (d2 < bd[0]) { bd[0] = d2; bi[0] = m; }
        }
    }
    int* op = knn_out + (size_t)(b * N_ + n0) * K_;
#pragma unroll
    for (int j = 0; j < K_; ++j) op[j] = bi[j];
}

// ---------------------------------------------------------------------------
// Fused edge-MLP kernel: one wave per point (16 edges x 256 features in
// wave-private LDS -> zero barriers). Lane computes 16 rows x 4 cols.
// ---------------------------------------------------------------------------
__device__ __forceinline__ float gelu_exact(float v) {
    return 0.5f * v * (1.0f + erff(v * 0.70710678118654752440f));
}

template <bool WRITEBACK>
__device__ __forceinline__ void mlp_layer(float (&H)[K_][E_], int lane,
        const float* __restrict__ W, const float* __restrict__ bias,
        const float* __restrict__ g, const float* __restrict__ be,
        float (&acc)[K_][4])
{
    const float4* __restrict__ W4 = (const float4*)W;
#pragma unroll
    for (int r = 0; r < K_; ++r) {
        acc[r][0] = 0.f; acc[r][1] = 0.f; acc[r][2] = 0.f; acc[r][3] = 0.f;
    }
    // manual W prefetch one k-step ahead (hide L2 latency at 2 waves/SIMD occ.)
    float4 w0 = W4[0 * (E_ / 4) + lane];
    float4 w1 = W4[1 * (E_ / 4) + lane];
    float4 w2 = W4[2 * (E_ / 4) + lane];
    float4 w3 = W4[3 * (E_ / 4) + lane];
#pragma unroll 1
    for (int kk = 0; kk < E_ / 4; ++kk) {
        const float4 cw0 = w0, cw1 = w1, cw2 = w2, cw3 = w3;
        if (kk + 1 < E_ / 4) {
            w0 = W4[(4 * kk + 4) * (E_ / 4) + lane];
            w1 = W4[(4 * kk + 5) * (E_ / 4) + lane];
            w2 = W4[(4 * kk + 6) * (E_ / 4) + lane];
            w3 = W4[(4 * kk + 7) * (E_ / 4) + lane];
        }
#pragma unroll
        for (int r = 0; r < K_; ++r) {
            const float4 h = *(const float4*)&H[r][4 * kk];   // wave-uniform: LDS broadcast
            acc[r][0] += h.x * cw0.x + h.y * cw1.x + h.z * cw2.x + h.w * cw3.x;
            acc[r][1] += h.x * cw0.y + h.y * cw1.y + h.z * cw2.y + h.w * cw3.y;
            acc[r][2] += h.x * cw0.z + h.y * cw1.z + h.z * cw2.z + h.w * cw3.z;
            acc[r][3] += h.x * cw0.w + h.y * cw1.w + h.z * cw2.w + h.w * cw3.w;
        }
    }
    const float4 bv  = ((const float4*)bias)[lane];
    const float4 gv  = ((const float4*)g)[lane];
    const float4 bev = ((const float4*)be)[lane];
#pragma unroll
    for (int r = 0; r < K_; ++r) {
        float v0 = acc[r][0] + bv.x;
        float v1 = acc[r][1] + bv.y;
        float v2 = acc[r][2] + bv.z;
        float v3 = acc[r][3] + bv.w;
        float s = v0 + v1 + v2 + v3;
#pragma unroll
        for (int off = 32; off > 0; off >>= 1) s += __shfl_xor(s, off, 64);
        const float mu = s * (1.0f / E_);
        v0 -= mu; v1 -= mu; v2 -= mu; v3 -= mu;
        float q = v0 * v0 + v1 * v1 + v2 * v2 + v3 * v3;
#pragma unroll
        for (int off = 32; off > 0; off >>= 1) q += __shfl_xor(q, off, 64);
        const float rstd = rsqrtf(q * (1.0f / E_) + LN_EPS);
        v0 = v0 * rstd * gv.x + bev.x;
        v1 = v1 * rstd * gv.y + bev.y;
        v2 = v2 * rstd * gv.z + bev.z;
        v3 = v3 * rstd * gv.w + bev.w;
        acc[r][0] = gelu_exact(v0);
        acc[r][1] = gelu_exact(v1);
        acc[r][2] = gelu_exact(v2);
        acc[r][3] = gelu_exact(v3);
    }
    if (WRITEBACK) {
        const int c0 = lane * 4;
#pragma unroll
        for (int r = 0; r < K_; ++r) {
            float4 v; v.x = acc[r][0]; v.y = acc[r][1]; v.z = acc[r][2]; v.w = acc[r][3];
            *(float4*)&H[r][c0] = v;
        }
    }
}

__global__ __launch_bounds__(256) void edgeconv_kernel(
    const float* __restrict__ x, const int* __restrict__ knn,
    const float* __restrict__ W1, const float* __restrict__ b1,
    const float* __restrict__ g1, const float* __restrict__ be1,
    const float* __restrict__ W2, const float* __restrict__ b2,
    const float* __restrict__ g2, const float* __restrict__ be2,
    const float* __restrict__ W3, const float* __restrict__ b3,
    const float* __restrict__ g3, const float* __restrict__ be3,
    const float* __restrict__ Ws, const float* __restrict__ bs,
    float* __restrict__ out)
{
    __shared__ float Hs[4][K_][E_];     // 64 KiB: 4 waves x (16x256 f32)
    const int wave = threadIdx.x >> 6;
    const int lane = threadIdx.x & 63;
    const int p = blockIdx.x * 4 + wave;
    const int b = p >> 11;
    const int n = p & (N_ - 1);
    float (&H)[K_][E_] = Hs[wave];
    const float4* __restrict__ xrow4 = (const float4*)(x + (size_t)(b * N_ + n) * D_);

    // ---- build edge features: H[k][0:128]=central, H[k][128:256]=nbr-central
    {
        const int j = lane & 31;
        const float4 c4 = xrow4[j];
        const int* kp = knn + (size_t)p * K_;
        for (int k = 0; k < K_; ++k) {
            const int ik = kp[k];
            if (lane < 32) {
                *(float4*)&H[k][4 * j] = c4;
            } else {
                const float4 n4 = ((const float4*)(x + (size_t)(b * N_ + ik) * D_))[j];
                float4 d4;
                d4.x = n4.x - c4.x; d4.y = n4.y - c4.y;
                d4.z = n4.z - c4.z; d4.w = n4.w - c4.w;
                *(float4*)&H[k][D_ + 4 * j] = d4;
            }
        }
    }
    // LDS region is wave-private; wave lockstep + in-order DS => no barriers.

    float acc[K_][4];
    mlp_layer<true >(H, lane, W1, b1, g1, be1, acc);
    mlp_layer<true >(H, lane, W2, b2, g2, be2, acc);
    mlp_layer<false>(H, lane, W3, b3, g3, be3, acc);

    // ---- max over K neighbors ----
    float a0 = acc[0][0], a1 = acc[0][1], a2 = acc[0][2], a3 = acc[0][3];
#pragma unroll
    for (int r = 1; r < K_; ++r) {
        a0 = fmaxf(a0, acc[r][0]); a1 = fmaxf(a1, acc[r][1]);
        a2 = fmaxf(a2, acc[r][2]); a3 = fmaxf(a3, acc[r][3]);
    }
    // ---- shortcut: x @ Ws ----
    const float4* __restrict__ Ws4 = (const float4*)Ws;
    float s0 = 0.f, s1 = 0.f, s2 = 0.f, s3 = 0.f;
#pragma unroll 1
    for (int dd = 0; dd < D_ / 4; ++dd) {
        const float4 xv = xrow4[dd];
        const float4 u0 = Ws4[(4 * dd + 0) * (E_ / 4) + lane];
        const float4 u1 = Ws4[(4 * dd + 1) * (E_ / 4) + lane];
        const float4 u2 = Ws4[(4 * dd + 2) * (E_ / 4) + lane];
        const float4 u3 = Ws4[(4 * dd + 3) * (E_ / 4) + lane];
        s0 += xv.x * u0.x + xv.y * u1.x + xv.z * u2.x + xv.w * u3.x;
        s1 += xv.x * u0.y + xv.y * u1.y + xv.z * u2.y + xv.w * u3.y;
        s2 += xv.x * u0.z + xv.y * u1.z + xv.z * u2.z + xv.w * u3.z;
        s3 += xv.x * u0.w + xv.y * u1.w + xv.z * u2.w + xv.w * u3.w;
    }
    const float4 bsv = ((const float4*)bs)[lane];
    float4 o;
    o.x = gelu_exact(a0 + s0 + bsv.x);
    o.y = gelu_exact(a1 + s1 + bsv.y);
    o.z = gelu_exact(a2 + s2 + bsv.z);
    o.w = gelu_exact(a3 + s3 + bsv.w);
    ((float4*)out)[(size_t)(b * N_ + n) * (E_ / 4) + lane] = o;
}

extern "C" void kernel_launch(void* const* d_in, const int* in_sizes, int n_in,
                              void* d_out, int out_size, void* d_ws, size_t ws_size,
                              hipStream_t stream) {
    const float* x      = (const float*)d_in[0];
    const float* coords = (const float*)d_in[1];
    const float* W1  = (const float*)d_in[2];
    const float* b1  = (const float*)d_in[3];
    const float* g1  = (const float*)d_in[4];
    const float* be1 = (const float*)d_in[5];
    const float* W2  = (const float*)d_in[6];
    const float* b2  = (const float*)d_in[7];
    const float* g2  = (const float*)d_in[8];
    const float* be2 = (const float*)d_in[9];
    const float* W3  = (const float*)d_in[10];
    const float* b3  = (const float*)d_in[11];
    const float* g3  = (const float*)d_in[12];
    const float* be3 = (const float*)d_in[13];
    const float* Ws  = (const float*)d_in[14];
    const float* bs  = (const float*)d_in[15];
    float* out = (float*)d_out;
    int* knn = (int*)d_ws;   // B*N*K ints = 1 MiB

    knn_topk_kernel<<<B_ * (N_ / 64), 64, 0, stream>>>(coords, knn);
    edgeconv_kernel<<<(B_ * N_) / 4, 256, 0, stream>>>(
        x, knn, W1, b1, g1, be1, W2, b2, g2, be2, W3, b3, g3, be3, Ws, bs, out);
}

// Round 3
// 1838.631 us; speedup vs baseline: 1.4988x; 1.4988x over previous
//
#include <hip/hip_runtime.h>
#include <math.h>

#define B_ 8
#define N_ 2048
#define D_ 128
#define E_ 256
#define K_ 16
#define LN_EPS 1e-5f

typedef short bf16x8 __attribute__((ext_vector_type(8)));
typedef float f32x4 __attribute__((ext_vector_type(4)));

// ---------------------------------------------------------------------------
// Reference-matching f32 distance: d2 = (sq_n + sq_m) - 2*dot, each op f32,
// NO FMA contraction (matches numpy expanded-form rounding; determines the
// top-16 set at near-tie boundaries).
// ---------------------------------------------------------------------------
__device__ __forceinline__ float sq3_ref(float x, float y, float z) {
#pragma clang fp contract(off)
    float s = x * x + y * y;
    s = s + z * z;
    return s;
}
__device__ __forceinline__ float d2_ref(float qx, float qy, float qz, float sqq,
                                        float mx, float my, float mz, float sqm) {
#pragma clang fp contract(off)
    float dot = mx * qx + my * qy;
    dot = dot + mz * qz;
    float t1 = sqq + sqm;
    float t2 = 2.0f * dot;
    float d2 = t1 - t2;
    return d2 > 0.0f ? d2 : 0.0f;
}

__device__ __forceinline__ unsigned short f2bf(float x) {
    unsigned u = __float_as_uint(x);
    unsigned r = (u + 0x7FFFu + ((u >> 16) & 1u)) >> 16;   // RTNE
    return (unsigned short)r;
}
__device__ __forceinline__ unsigned pack2(float a, float b) {
    return (unsigned)f2bf(a) | ((unsigned)f2bf(b) << 16);
}

// exact-GELU via A&S 7.1.26 erf (|eps| < 1.5e-7), branchless, ~15 VALU ops
__device__ __forceinline__ float gelu_fast(float v) {
    const float z  = v * 0.70710678118654752440f;
    const float az = fabsf(z);
    const float t  = __fdividef(1.0f, fmaf(0.3275911f, az, 1.0f));
    float p = fmaf(1.061405429f, t, -1.453152027f);
    p = fmaf(p, t, 1.421413741f);
    p = fmaf(p, t, -0.284496736f);
    p = fmaf(p, t, 0.254829592f);
    p = p * t;
    const float ex = __expf(-az * az);
    float erfv = fmaf(-p, ex, 1.0f);
    erfv = (z < 0.0f) ? -erfv : erfv;
    return 0.5f * v * (1.0f + erfv);
}

// ---------------------------------------------------------------------------
// Kernel 1: kNN top-16 via branch-free radix select. One wave per query,
// 8 queries per 512-thread block; coords+sq staged in LDS (32 KiB).
// 32 keys/lane in registers; MSB-first bit descent; ties by lowest index
// (matches stable lax.top_k). Output order within the 16 is arbitrary
// (consumer max-aggregates -> set semantics).
// ---------------------------------------------------------------------------
__global__ __launch_bounds__(512) void knn_select_kernel(const float* __restrict__ coords,
                                                         int* __restrict__ knn_out) {
    __shared__ float lc[3][N_];
    __shared__ float lsq[N_];
    __shared__ int cnt[8];
    const int wave = threadIdx.x >> 6;
    const int lane = threadIdx.x & 63;
    const int p = blockIdx.x * 8 + wave;
    const int b = p >> 11;
    const int n0 = p & (N_ - 1);
    const float* cb = coords + (size_t)b * N_ * 3;
    for (int i = threadIdx.x; i < N_ * 3; i += 512) {
        int n = i / 3, c = i - 3 * n;
        lc[c][n] = cb[i];
    }
    __syncthreads();
    for (int n = threadIdx.x; n < N_; n += 512) lsq[n] = sq3_ref(lc[0][n], lc[1][n], lc[2][n]);
    __syncthreads();

    const float qx = lc[0][n0], qy = lc[1][n0], qz = lc[2][n0], sqq = lsq[n0];
    unsigned key[32];
#pragma unroll
    for (int j = 0; j < 32; ++j) {
        const int m = j * 64 + lane;
        key[j] = __float_as_uint(d2_ref(qx, qy, qz, sqq, lc[0][m], lc[1][m], lc[2][m], lsq[m]));
    }

    // MSB-first radix descent for the 16th-smallest key
    unsigned prefix = 0;
    int rem = K_, setc = N_, bshift = 0;
    bool bounded = false;
    for (int bit = 31; bit >= 0; --bit) {
        const unsigned want = prefix << 1;
        int c = 0;
#pragma unroll
        for (int j = 0; j < 32; ++j) c += ((key[j] >> bit) == want) ? 1 : 0;
        for (int off = 1; off < 64; off <<= 1) c += __shfl_xor(c, off, 64);
        if (rem <= c) { prefix = want; setc = c; }
        else          { prefix = want | 1u; rem -= c; setc -= c; }
        bshift = bit;
        if (setc == rem) { bounded = true; break; }
    }

    if (lane == 0) cnt[wave] = 0;
    int* op = knn_out + (size_t)p * K_;
    const unsigned long long BE = bounded ? (((unsigned long long)prefix + 1ull) << bshift)
                                          : (unsigned long long)prefix;
#pragma unroll
    for (int j = 0; j < 32; ++j) {
        if ((unsigned long long)key[j] < BE) {
            int s = atomicAdd(&cnt[wave], 1);
            op[s] = j * 64 + lane;
        }
    }
    if (!bounded) {
        const unsigned V = prefix;
#pragma unroll
        for (int j = 0; j < 32; ++j) {
            if (rem > 0) {
                unsigned long long mask = __ballot(key[j] == V);
                int below = __popcll(mask & ((1ull << lane) - 1ull));
                if (key[j] == V && below < rem) {
                    int s = atomicAdd(&cnt[wave], 1);
                    op[s] = j * 64 + lane;
                }
                rem -= __popcll(mask);
            }
        }
    }
}

// ---------------------------------------------------------------------------
// Kernel 2: prepack W1/W2/W3 (f32 [256 x 256], rows=in, cols=out) into bf16
// MFMA A-fragments of W^T:  WF[((L*128 + mt*8 + kt)*64 + lane)*8 + i]
//   = bf16( W_L[32kt + 8*(lane>>4) + i][16mt + (lane&15)] )
// ---------------------------------------------------------------------------
__global__ __launch_bounds__(64) void wprep_kernel(const float* __restrict__ W1,
                                                   const float* __restrict__ W2,
                                                   const float* __restrict__ W3,
                                                   short* __restrict__ WF) {
    const int bi = blockIdx.x;          // 0..383
    const int L = bi >> 7;
    const int t = bi & 127;             // mt*8 + kt
    const int mt = t >> 3, kt = t & 7;
    const float* W = (L == 0) ? W1 : (L == 1) ? W2 : W3;
    const int lane = threadIdx.x;
    const int g = lane >> 4, e = lane & 15;
    const int f = 16 * mt + e;
    unsigned v[4];
#pragma unroll
    for (int i2 = 0; i2 < 4; ++i2) {
        const int k = 32 * kt + 8 * g + 2 * i2;
        v[i2] = pack2(W[(size_t)k * E_ + f], W[(size_t)(k + 1) * E_ + f]);
    }
    uint4 u; u.x = v[0]; u.y = v[1]; u.z = v[2]; u.w = v[3];
    *reinterpret_cast<uint4*>(WF + ((size_t)bi * 64 + lane) * 8) = u;
}

// ---------------------------------------------------------------------------
// Kernel 3: fused edge-MLP, MFMA version. One wave = 2 points; wave-private
// LDS holds H^T (bf16, [16 edges][256 feat], XOR-swizzled) per point.
// Transposed GEMM: C^T = W^T @ H^T; C/D layout (m89): col=lane&15 (edge),
// row=4*(lane>>4)+reg (feature-within-mt-tile)  -> each lane owns ONE edge.
// LN reduce over features = 2x shfl_xor(16,32). No block barriers anywhere.
// ---------------------------------------------------------------------------
template <int LAST>
__device__ __forceinline__ void ln_gelu(f32x4 (&acc)[16], int e, int g,
                                        const float* __restrict__ bL,
                                        const float* __restrict__ gL,
                                        const float* __restrict__ beL,
                                        char* HB, unsigned swz) {
    float s = 0.f;
#pragma unroll
    for (int mt = 0; mt < 16; ++mt) {
        const float4 bv = *(const float4*)(bL + 16 * mt + 4 * g);
        acc[mt][0] += bv.x; acc[mt][1] += bv.y; acc[mt][2] += bv.z; acc[mt][3] += bv.w;
        s += acc[mt][0] + acc[mt][1] + acc[mt][2] + acc[mt][3];
    }
    s += __shfl_xor(s, 16, 64);
    s += __shfl_xor(s, 32, 64);
    const float mu = s * (1.0f / 256.0f);
    float q = 0.f;
#pragma unroll
    for (int mt = 0; mt < 16; ++mt) {
#pragma unroll
        for (int i = 0; i < 4; ++i) { const float d = acc[mt][i] - mu; q = fmaf(d, d, q); }
    }
    q += __shfl_xor(q, 16, 64);
    q += __shfl_xor(q, 32, 64);
    const float rstd = rsqrtf(q * (1.0f / 256.0f) + LN_EPS);
#pragma unroll
    for (int mt = 0; mt < 16; ++mt) {
        const float4 gv  = *(const float4*)(gL + 16 * mt + 4 * g);
        const float4 bev = *(const float4*)(beL + 16 * mt + 4 * g);
        const float r0 = gelu_fast(fmaf((acc[mt][0] - mu) * rstd, gv.x, bev.x));
        const float r1 = gelu_fast(fmaf((acc[mt][1] - mu) * rstd, gv.y, bev.y));
        const float r2 = gelu_fast(fmaf((acc[mt][2] - mu) * rstd, gv.z, bev.z));
        const float r3 = gelu_fast(fmaf((acc[mt][3] - mu) * rstd, gv.w, bev.w));
        if (LAST) {
            acc[mt][0] = r0; acc[mt][1] = r1; acc[mt][2] = r2; acc[mt][3] = r3;
        } else {
            *(uint2*)(HB + (((e << 9) + (mt << 5) + (g << 3)) ^ swz)) =
                make_uint2(pack2(r0, r1), pack2(r2, r3));
        }
    }
}

__global__ __launch_bounds__(256, 2) void edgeconv_mfma(
    const float* __restrict__ x, const int* __restrict__ knn,
    const short* __restrict__ WF,
    const float* __restrict__ b1, const float* __restrict__ g1, const float* __restrict__ be1,
    const float* __restrict__ b2, const float* __restrict__ g2, const float* __restrict__ be2,
    const float* __restrict__ b3, const float* __restrict__ g3, const float* __restrict__ be3,
    const float* __restrict__ Ws, const float* __restrict__ bs,
    float* __restrict__ out)
{
    __shared__ short Hl[4][2][4096];    // 64 KiB: 4 waves x 2 points x (16x256 bf16)
    const int wave = threadIdx.x >> 6;
    const int lane = threadIdx.x & 63;
    const int e = lane & 15;            // edge (GEMM) / quarter-owner (build)
    const int g = lane >> 4;            // k-group / feature-quarter
    const int p0 = (blockIdx.x * 4 + wave) * 2;
    const int b = p0 >> 11;
    const unsigned swz = (unsigned)((e & 7) << 4);
    char* H0 = (char*)&Hl[wave][0][0];
    char* H1 = (char*)&Hl[wave][1][0];

    // ---- edge build (both points): H[e][0:128]=central, H[e][128:256]=nbr-central
#pragma unroll
    for (int pp = 0; pp < 2; ++pp) {
        const int p = p0 + pp;
        const int n = p & (N_ - 1);
        const float4* xr = (const float4*)(x + ((size_t)b * N_ + n) * D_);
        const int nb = knn[(size_t)p * K_ + e];
        const float4* nr = (const float4*)(x + ((size_t)b * N_ + nb) * D_);
        char* HB = pp ? H1 : H0;
#pragma unroll
        for (int c2 = 0; c2 < 8; ++c2) {
            const float4 cv = xr[8 * g + c2];
            const float4 nv = nr[8 * g + c2];
            const int base = (e << 9) + (g << 6) + (c2 << 3);
            *(uint2*)(HB + (base ^ swz)) = make_uint2(pack2(cv.x, cv.y), pack2(cv.z, cv.w));
            *(uint2*)(HB + ((base + 256) ^ swz)) =
                make_uint2(pack2(nv.x - cv.x, nv.y - cv.y), pack2(nv.z - cv.z, nv.w - cv.w));
        }
    }
    asm volatile("s_waitcnt lgkmcnt(0)" ::: "memory");

    f32x4 acc0[16], acc1[16];

    for (int L = 0; L < 3; ++L) {
        const short* WFL = WF + (size_t)L * 128 * 512;
        const float* bL  = (L == 0) ? b1  : (L == 1) ? b2  : b3;
        const float* gL  = (L == 0) ? g1  : (L == 1) ? g2  : g3;
        const float* beL = (L == 0) ? be1 : (L == 1) ? be2 : be3;

        const f32x4 z = {0.f, 0.f, 0.f, 0.f};
#pragma unroll
        for (int mt = 0; mt < 16; ++mt) { acc0[mt] = z; acc1[mt] = z; }

        const int offB = (e << 9) + (g << 4);
        bf16x8 Bc0 = *(const bf16x8*)(H0 + (offB ^ swz));
        bf16x8 Bc1 = *(const bf16x8*)(H1 + (offB ^ swz));
#pragma unroll 2
        for (int kt = 0; kt < 8; ++kt) {
            bf16x8 Bn0, Bn1;
            if (kt < 7) {
                Bn0 = *(const bf16x8*)(H0 + ((offB + ((kt + 1) << 6)) ^ swz));
                Bn1 = *(const bf16x8*)(H1 + ((offB + ((kt + 1) << 6)) ^ swz));
            }
#pragma unroll
            for (int mt = 0; mt < 16; ++mt) {
                const bf16x8 a = *(const bf16x8*)(WFL + (size_t)(((mt << 3) + kt) << 9) + (lane << 3));
                acc0[mt] = __builtin_amdgcn_mfma_f32_16x16x32_bf16(a, Bc0, acc0[mt], 0, 0, 0);
                acc1[mt] = __builtin_amdgcn_mfma_f32_16x16x32_bf16(a, Bc1, acc1[mt], 0, 0, 0);
            }
            if (kt < 7) { Bc0 = Bn0; Bc1 = Bn1; }
        }

        if (L < 2) {
            ln_gelu<0>(acc0, e, g, bL, gL, beL, H0, swz);
            ln_gelu<0>(acc1, e, g, bL, gL, beL, H1, swz);
            asm volatile("s_waitcnt lgkmcnt(0)" ::: "memory");
        } else {
            ln_gelu<1>(acc0, e, g, bL, gL, beL, H0, swz);
            ln_gelu<1>(acc1, e, g, bL, gL, beL, H1, swz);
        }
    }

    // ---- max over 16 edges (reduce across e-lanes: xor 1,2,4,8) ----
#pragma unroll
    for (int mt = 0; mt < 16; ++mt) {
#pragma unroll
        for (int i = 0; i < 4; ++i) {
            float v0 = acc0[mt][i], v1 = acc1[mt][i];
#pragma unroll
            for (int off = 1; off < 16; off <<= 1) {
                v0 = fmaxf(v0, __shfl_xor(v0, off, 64));
                v1 = fmaxf(v1, __shfl_xor(v1, off, 64));
            }
            acc0[mt][i] = v0; acc1[mt][i] = v1;
        }
    }
    // lane (e,g) takes tile mt == e  -> handles features f0 = 16e+4g .. +3
    f32x4 sel0 = acc0[0], sel1 = acc1[0];
#pragma unroll
    for (int mt = 1; mt < 16; ++mt) {
        if (e == mt) { sel0 = acc0[mt]; sel1 = acc1[mt]; }
    }

    // ---- shortcut x @ Ws (exact f32), streamed once for both points ----
    const int f0 = 16 * e + 4 * g;
    const float* xr0 = x + ((size_t)b * N_ + (p0 & (N_ - 1))) * D_;
    const float* xr1 = xr0 + D_;
    const float4* Ws4 = (const float4*)Ws;
    float4 s0 = make_float4(0.f, 0.f, 0.f, 0.f);
    float4 s1 = make_float4(0.f, 0.f, 0.f, 0.f);
#pragma unroll 4
    for (int k = 0; k < 128; ++k) {
        const float4 w4 = Ws4[k * 64 + 4 * e + g];
        const float x0 = xr0[k], x1 = xr1[k];
        s0.x = fmaf(x0, w4.x, s0.x); s0.y = fmaf(x0, w4.y, s0.y);
        s0.z = fmaf(x0, w4.z, s0.z); s0.w = fmaf(x0, w4.w, s0.w);
        s1.x = fmaf(x1, w4.x, s1.x); s1.y = fmaf(x1, w4.y, s1.y);
        s1.z = fmaf(x1, w4.z, s1.z); s1.w = fmaf(x1, w4.w, s1.w);
    }
    const float4 bsv = *(const float4*)(bs + f0);
    float4 o0, o1;
    o0.x = gelu_fast(sel0[0] + s0.x + bsv.x);
    o0.y = gelu_fast(sel0[1] + s0.y + bsv.y);
    o0.z = gelu_fast(sel0[2] + s0.z + bsv.z);
    o0.w = gelu_fast(sel0[3] + s0.w + bsv.w);
    o1.x = gelu_fast(sel1[0] + s1.x + bsv.x);
    o1.y = gelu_fast(sel1[1] + s1.y + bsv.y);
    o1.z = gelu_fast(sel1[2] + s1.z + bsv.z);
    o1.w = gelu_fast(sel1[3] + s1.w + bsv.w);
    *(float4*)(out + (size_t)p0 * E_ + f0) = o0;
    *(float4*)(out + (size_t)(p0 + 1) * E_ + f0) = o1;
}

extern "C" void kernel_launch(void* const* d_in, const int* in_sizes, int n_in,
                              void* d_out, int out_size, void* d_ws, size_t ws_size,
                              hipStream_t stream) {
    const float* x      = (const float*)d_in[0];
    const float* coords = (const float*)d_in[1];
    const float* W1  = (const float*)d_in[2];
    const float* b1  = (const float*)d_in[3];
    const float* g1  = (const float*)d_in[4];
    const float* be1 = (const float*)d_in[5];
    const float* W2  = (const float*)d_in[6];
    const float* b2  = (const float*)d_in[7];
    const float* g2  = (const float*)d_in[8];
    const float* be2 = (const float*)d_in[9];
    const float* W3  = (const float*)d_in[10];
    const float* b3  = (const float*)d_in[11];
    const float* g3  = (const float*)d_in[12];
    const float* be3 = (const float*)d_in[13];
    const float* Ws  = (const float*)d_in[14];
    const float* bs  = (const float*)d_in[15];
    float* out = (float*)d_out;

    int*   knn = (int*)d_ws;                          // 1 MiB
    short* WF  = (short*)((char*)d_ws + (1 << 20));   // 384 KiB bf16 fragments

    wprep_kernel<<<384, 64, 0, stream>>>(W1, W2, W3, WF);
    knn_select_kernel<<<B_ * (N_ / 8), 512, 0, stream>>>(coords, knn);
    edgeconv_mfma<<<(B_ * N_) / 8, 256, 0, stream>>>(
        x, knn, WF, b1, g1, be1, b2, g2, be2, b3, g3, be3, Ws, bs, out);
}

// Round 4
// 612.061 us; speedup vs baseline: 4.5023x; 3.0040x over previous
//
#include <hip/hip_runtime.h>
#include <math.h>

#define B_ 8
#define N_ 2048
#define D_ 128
#define E_ 256
#define K_ 16
#define LN_EPS 1e-5f

typedef short bf16x8 __attribute__((ext_vector_type(8)));
typedef float f32x4 __attribute__((ext_vector_type(4)));

// ---------------------------------------------------------------------------
// Reference-matching f32 distance: d2 = (sq_n + sq_m) - 2*dot, each op f32,
// NO FMA contraction (matches numpy expanded-form rounding; determines the
// top-16 set at near-tie boundaries).
// ---------------------------------------------------------------------------
__device__ __forceinline__ float sq3_ref(float x, float y, float z) {
#pragma clang fp contract(off)
    float s = x * x + y * y;
    s = s + z * z;
    return s;
}
__device__ __forceinline__ float d2_ref(float qx, float qy, float qz, float sqq,
                                        float mx, float my, float mz, float sqm) {
#pragma clang fp contract(off)
    float dot = mx * qx + my * qy;
    dot = dot + mz * qz;
    float t1 = sqq + sqm;
    float t2 = 2.0f * dot;
    float d2 = t1 - t2;
    return d2 > 0.0f ? d2 : 0.0f;
}

__device__ __forceinline__ unsigned short f2bf(float x) {
    unsigned u = __float_as_uint(x);
    unsigned r = (u + 0x7FFFu + ((u >> 16) & 1u)) >> 16;   // RTNE
    return (unsigned short)r;
}
__device__ __forceinline__ unsigned pack2(float a, float b) {
    return (unsigned)f2bf(a) | ((unsigned)f2bf(b) << 16);
}

// exact-GELU via A&S 7.1.26 erf (|eps| < 1.5e-7), branchless
__device__ __forceinline__ float gelu_fast(float v) {
    const float z  = v * 0.70710678118654752440f;
    const float az = fabsf(z);
    const float t  = __fdividef(1.0f, fmaf(0.3275911f, az, 1.0f));
    float p = fmaf(1.061405429f, t, -1.453152027f);
    p = fmaf(p, t, 1.421413741f);
    p = fmaf(p, t, -0.284496736f);
    p = fmaf(p, t, 0.254829592f);
    p = p * t;
    const float ex = __expf(-az * az);
    float erfv = fmaf(-p, ex, 1.0f);
    erfv = (z < 0.0f) ? -erfv : erfv;
    return 0.5f * v * (1.0f + erfv);
}

// ---------------------------------------------------------------------------
// Kernel 1: kNN top-16 via branch-free radix select (one wave per query).
// ---------------------------------------------------------------------------
__global__ __launch_bounds__(512) void knn_select_kernel(const float* __restrict__ coords,
                                                         int* __restrict__ knn_out) {
    __shared__ float lc[3][N_];
    __shared__ float lsq[N_];
    __shared__ int cnt[8];
    const int wave = threadIdx.x >> 6;
    const int lane = threadIdx.x & 63;
    const int p = blockIdx.x * 8 + wave;
    const int b = p >> 11;
    const int n0 = p & (N_ - 1);
    const float* cb = coords + (size_t)b * N_ * 3;
    for (int i = threadIdx.x; i < N_ * 3; i += 512) {
        int n = i / 3, c = i - 3 * n;
        lc[c][n] = cb[i];
    }
    __syncthreads();
    for (int n = threadIdx.x; n < N_; n += 512) lsq[n] = sq3_ref(lc[0][n], lc[1][n], lc[2][n]);
    __syncthreads();

    const float qx = lc[0][n0], qy = lc[1][n0], qz = lc[2][n0], sqq = lsq[n0];
    unsigned key[32];
#pragma unroll
    for (int j = 0; j < 32; ++j) {
        const int m = j * 64 + lane;
        key[j] = __float_as_uint(d2_ref(qx, qy, qz, sqq, lc[0][m], lc[1][m], lc[2][m], lsq[m]));
    }

    unsigned prefix = 0;
    int rem = K_, setc = N_, bshift = 0;
    bool bounded = false;
    for (int bit = 31; bit >= 0; --bit) {
        const unsigned want = prefix << 1;
        int c = 0;
#pragma unroll
        for (int j = 0; j < 32; ++j) c += ((key[j] >> bit) == want) ? 1 : 0;
        for (int off = 1; off < 64; off <<= 1) c += __shfl_xor(c, off, 64);
        if (rem <= c) { prefix = want; setc = c; }
        else          { prefix = want | 1u; rem -= c; setc -= c; }
        bshift = bit;
        if (setc == rem) { bounded = true; break; }
    }

    if (lane == 0) cnt[wave] = 0;
    int* op = knn_out + (size_t)p * K_;
    const unsigned long long BE = bounded ? (((unsigned long long)prefix + 1ull) << bshift)
                                          : (unsigned long long)prefix;
#pragma unroll
    for (int j = 0; j < 32; ++j) {
        if ((unsigned long long)key[j] < BE) {
            int s = atomicAdd(&cnt[wave], 1);
            op[s] = j * 64 + lane;
        }
    }
    if (!bounded) {
        const unsigned V = prefix;
#pragma unroll
        for (int j = 0; j < 32; ++j) {
            if (rem > 0) {
                unsigned long long mask = __ballot(key[j] == V);
                int below = __popcll(mask & ((1ull << lane) - 1ull));
                if (key[j] == V && below < rem) {
                    int s = atomicAdd(&cnt[wave], 1);
                    op[s] = j * 64 + lane;
                }
                rem -= __popcll(mask);
            }
        }
    }
}

// ---------------------------------------------------------------------------
// Kernel 2: prepack W1/W2/W3 and Ws into bf16 MFMA A-fragments (W^T form).
//   layers: WF[(L*128 + mt*8 + kt)*64*8 ...] = W_L[32kt+8g+i][16mt+e]
//   Ws:     WF[(384   + mt*4 + kt)*64*8 ...] = Ws [32kt+8g+i][16mt+e]
// ---------------------------------------------------------------------------
__global__ __launch_bounds__(64) void wprep_kernel(const float* __restrict__ W1,
                                                   const float* __restrict__ W2,
                                                   const float* __restrict__ W3,
                                                   const float* __restrict__ Ws,
                                                   short* __restrict__ WF) {
    const int bi = blockIdx.x;          // 0..447
    const int lane = threadIdx.x;
    const int g = lane >> 4, e = lane & 15;
    const float* W;
    int mt, kt;
    if (bi < 384) {
        const int L = bi >> 7;
        const int t = bi & 127;
        mt = t >> 3; kt = t & 7;
        W = (L == 0) ? W1 : (L == 1) ? W2 : W3;
    } else {
        const int t = bi - 384;
        mt = t >> 2; kt = t & 3;
        W = Ws;
    }
    const int f = 16 * mt + e;
    unsigned v[4];
#pragma unroll
    for (int i2 = 0; i2 < 4; ++i2) {
        const int k = 32 * kt + 8 * g + 2 * i2;
        v[i2] = pack2(W[(size_t)k * E_ + f], W[(size_t)(k + 1) * E_ + f]);
    }
    uint4 u; u.x = v[0]; u.y = v[1]; u.z = v[2]; u.w = v[3];
    *reinterpret_cast<uint4*>(WF + ((size_t)bi * 64 + lane) * 8) = u;
}

// ---------------------------------------------------------------------------
// Kernel 3: fused edge-MLP, MFMA, ONE point per wave (no spill: acc = 64 VGPR).
// Wave-private LDS H^T [16 edges][256 feat] bf16 XOR-swizzled, zero barriers.
// C^T = W^T @ H^T; C/D: col(lane&15)=edge, row 4*(lane>>4)+i = feature ->
// each lane owns one edge; LN reduce = 2x shfl_xor(16,32).
// Shortcut x@Ws done as 4 extra kt MFMA steps against a broadcast bf16 x-row.
// ---------------------------------------------------------------------------
template <int LAST>
__device__ __forceinline__ void ln_gelu(f32x4 (&acc)[16], int e, int g,
                                        const float* __restrict__ bL,
                                        const float* __restrict__ gL,
                                        const float* __restrict__ beL,
                                        char* HB, unsigned swz) {
    float s = 0.f;
#pragma unroll
    for (int mt = 0; mt < 16; ++mt) {
        const float4 bv = *(const float4*)(bL + 16 * mt + 4 * g);
        acc[mt][0] += bv.x; acc[mt][1] += bv.y; acc[mt][2] += bv.z; acc[mt][3] += bv.w;
        s += acc[mt][0] + acc[mt][1] + acc[mt][2] + acc[mt][3];
    }
    s += __shfl_xor(s, 16, 64);
    s += __shfl_xor(s, 32, 64);
    const float mu = s * (1.0f / 256.0f);
    float q = 0.f;
#pragma unroll
    for (int mt = 0; mt < 16; ++mt) {
#pragma unroll
        for (int i = 0; i < 4; ++i) { const float d = acc[mt][i] - mu; q = fmaf(d, d, q); }
    }
    q += __shfl_xor(q, 16, 64);
    q += __shfl_xor(q, 32, 64);
    const float rstd = rsqrtf(q * (1.0f / 256.0f) + LN_EPS);
#pragma unroll
    for (int mt = 0; mt < 16; ++mt) {
        const float4 gv  = *(const float4*)(gL + 16 * mt + 4 * g);
        const float4 bev = *(const float4*)(beL + 16 * mt + 4 * g);
        const float r0 = gelu_fast(fmaf((acc[mt][0] - mu) * rstd, gv.x, bev.x));
        const float r1 = gelu_fast(fmaf((acc[mt][1] - mu) * rstd, gv.y, bev.y));
        const float r2 = gelu_fast(fmaf((acc[mt][2] - mu) * rstd, gv.z, bev.z));
        const float r3 = gelu_fast(fmaf((acc[mt][3] - mu) * rstd, gv.w, bev.w));
        if (LAST) {
            acc[mt][0] = r0; acc[mt][1] = r1; acc[mt][2] = r2; acc[mt][3] = r3;
        } else {
            *(uint2*)(HB + (((e << 9) + (mt << 5) + (g << 3)) ^ swz)) =
                make_uint2(pack2(r0, r1), pack2(r2, r3));
        }
    }
}

__global__ __launch_bounds__(256, 2) void edgeconv_mfma(
    const float* __restrict__ x, const int* __restrict__ knn,
    const short* __restrict__ WF,
    const float* __restrict__ b1, const float* __restrict__ g1, const float* __restrict__ be1,
    const float* __restrict__ b2, const float* __restrict__ g2, const float* __restrict__ be2,
    const float* __restrict__ b3, const float* __restrict__ g3, const float* __restrict__ be3,
    const float* __restrict__ bs,
    float* __restrict__ out)
{
    __shared__ short Hl[4][4096];       // 32 KiB: 4 waves x (16x256 bf16)
    __shared__ short Hx[4][128];        // 1 KiB: broadcast bf16 x-row per wave
    const int wave = threadIdx.x >> 6;
    const int lane = threadIdx.x & 63;
    const int e = lane & 15;
    const int g = lane >> 4;
    const int p = blockIdx.x * 4 + wave;
    const int b = p >> 11;
    const int n = p & (N_ - 1);
    const unsigned swz = (unsigned)((e & 7) << 4);
    char* H0 = (char*)&Hl[wave][0];
    char* XC = (char*)&Hx[wave][0];

    // ---- edge build: H[e][0:128]=central, H[e][128:256]=nbr-central
    {
        const float4* xr = (const float4*)(x + ((size_t)b * N_ + n) * D_);
        const int nb = knn[(size_t)p * K_ + e];
        const float4* nr = (const float4*)(x + ((size_t)b * N_ + nb) * D_);
#pragma unroll
        for (int c2 = 0; c2 < 8; ++c2) {
            const float4 cv = xr[8 * g + c2];
            const float4 nv = nr[8 * g + c2];
            const int base = (e << 9) + (g << 6) + (c2 << 3);
            const uint2 cpk = make_uint2(pack2(cv.x, cv.y), pack2(cv.z, cv.w));
            *(uint2*)(H0 + (base ^ swz)) = cpk;
            *(uint2*)(H0 + ((base + 256) ^ swz)) =
                make_uint2(pack2(nv.x - cv.x, nv.y - cv.y), pack2(nv.z - cv.z, nv.w - cv.w));
            if (e == 0) *(uint2*)(XC + (g << 6) + (c2 << 3)) = cpk;
        }
    }
    asm volatile("s_waitcnt lgkmcnt(0)" ::: "memory");

    f32x4 acc[16];

    for (int L = 0; L < 3; ++L) {
        const short* WFL = WF + (size_t)L * 128 * 512;
        const float* bL  = (L == 0) ? b1  : (L == 1) ? b2  : b3;
        const float* gL  = (L == 0) ? g1  : (L == 1) ? g2  : g3;
        const float* beL = (L == 0) ? be1 : (L == 1) ? be2 : be3;

        const f32x4 z = {0.f, 0.f, 0.f, 0.f};
#pragma unroll
        for (int mt = 0; mt < 16; ++mt) acc[mt] = z;

        const int offB = (e << 9) + (g << 4);
        bf16x8 Bc = *(const bf16x8*)(H0 + (offB ^ swz));
#pragma unroll 2
        for (int kt = 0; kt < 8; ++kt) {
            bf16x8 Bn;
            if (kt < 7) Bn = *(const bf16x8*)(H0 + ((offB + ((kt + 1) << 6)) ^ swz));
#pragma unroll
            for (int mt = 0; mt < 16; ++mt) {
                const bf16x8 a = *(const bf16x8*)(WFL + (size_t)(((mt << 3) + kt) << 9) + (lane << 3));
                acc[mt] = __builtin_amdgcn_mfma_f32_16x16x32_bf16(a, Bc, acc[mt], 0, 0, 0);
            }
            if (kt < 7) Bc = Bn;
        }

        if (L < 2) {
            ln_gelu<0>(acc, e, g, bL, gL, beL, H0, swz);
            asm volatile("s_waitcnt lgkmcnt(0)" ::: "memory");
        } else {
            ln_gelu<1>(acc, e, g, bL, gL, beL, H0, swz);
        }
    }

    // ---- max over 16 edges (reduce across e-lanes: xor 1,2,4,8) ----
#pragma unroll
    for (int mt = 0; mt < 16; ++mt) {
#pragma unroll
        for (int i = 0; i < 4; ++i) {
            float v0 = acc[mt][i];
#pragma unroll
            for (int off = 1; off < 16; off <<= 1) v0 = fmaxf(v0, __shfl_xor(v0, off, 64));
            acc[mt][i] = v0;
        }
    }
    f32x4 sel = acc[0];
#pragma unroll
    for (int mt = 1; mt < 16; ++mt) {
        if (e == mt) sel = acc[mt];
    }

    // ---- shortcut x @ Ws via MFMA against broadcast bf16 x-row ----
    const short* WSF = WF + (size_t)384 * 512;
    f32x4 scc[16];
    const f32x4 z = {0.f, 0.f, 0.f, 0.f};
#pragma unroll
    for (int mt = 0; mt < 16; ++mt) scc[mt] = z;
#pragma unroll
    for (int kt = 0; kt < 4; ++kt) {
        const bf16x8 bx = *(const bf16x8*)(XC + (kt << 6) + (g << 4));
#pragma unroll
        for (int mt = 0; mt < 16; ++mt) {
            const bf16x8 a = *(const bf16x8*)(WSF + (size_t)(((mt << 2) + kt) << 9) + (lane << 3));
            scc[mt] = __builtin_amdgcn_mfma_f32_16x16x32_bf16(a, bx, scc[mt], 0, 0, 0);
        }
    }
    f32x4 ssc = scc[0];
#pragma unroll
    for (int mt = 1; mt < 16; ++mt) {
        if (e == mt) ssc = scc[mt];
    }

    const int f0 = 16 * e + 4 * g;
    const float4 bsv = *(const float4*)(bs + f0);
    float4 o;
    o.x = gelu_fast(sel[0] + ssc[0] + bsv.x);
    o.y = gelu_fast(sel[1] + ssc[1] + bsv.y);
    o.z = gelu_fast(sel[2] + ssc[2] + bsv.z);
    o.w = gelu_fast(sel[3] + ssc[3] + bsv.w);
    *(float4*)(out + (size_t)p * E_ + f0) = o;
}

extern "C" void kernel_launch(void* const* d_in, const int* in_sizes, int n_in,
                              void* d_out, int out_size, void* d_ws, size_t ws_size,
                              hipStream_t stream) {
    const float* x      = (const float*)d_in[0];
    const float* coords = (const float*)d_in[1];
    const float* W1  = (const float*)d_in[2];
    const float* b1  = (const float*)d_in[3];
    const float* g1  = (const float*)d_in[4];
    const float* be1 = (const float*)d_in[5];
    const float* W2  = (const float*)d_in[6];
    const float* b2  = (const float*)d_in[7];
    const float* g2  = (const float*)d_in[8];
    const float* be2 = (const float*)d_in[9];
    const float* W3  = (const float*)d_in[10];
    const float* b3  = (const float*)d_in[11];
    const float* g3  = (const float*)d_in[12];
    const float* be3 = (const float*)d_in[13];
    const float* Ws  = (const float*)d_in[14];
    const float* bs  = (const float*)d_in[15];
    float* out = (float*)d_out;

    int*   knn = (int*)d_ws;                          // 1 MiB
    short* WF  = (short*)((char*)d_ws + (1 << 20));   // 448 KiB bf16 fragments

    wprep_kernel<<<448, 64, 0, stream>>>(W1, W2, W3, Ws, WF);
    knn_select_kernel<<<B_ * (N_ / 8), 512, 0, stream>>>(coords, knn);
    edgeconv_mfma<<<(B_ * N_) / 4, 256, 0, stream>>>(
        x, knn, WF, b1, g1, be1, b2, g2, be2, b3, g3, be3, bs, out);
}

// Round 5
// 483.269 us; speedup vs baseline: 5.7022x; 1.2665x over previous
//
#include <hip/hip_runtime.h>
#include <math.h>

#define B_ 8
#define N_ 2048
#define D_ 128
#define E_ 256
#define K_ 16
#define LN_EPS 1e-5f

typedef short bf16x8 __attribute__((ext_vector_type(8)));
typedef float f32x4 __attribute__((ext_vector_type(4)));

// ---------------------------------------------------------------------------
// Reference-matching f32 distance (expanded form, no FMA contraction).
// ---------------------------------------------------------------------------
__device__ __forceinline__ float sq3_ref(float x, float y, float z) {
#pragma clang fp contract(off)
    float s = x * x + y * y;
    s = s + z * z;
    return s;
}
__device__ __forceinline__ float d2_ref(float qx, float qy, float qz, float sqq,
                                        float mx, float my, float mz, float sqm) {
#pragma clang fp contract(off)
    float dot = mx * qx + my * qy;
    dot = dot + mz * qz;
    float t1 = sqq + sqm;
    float t2 = 2.0f * dot;
    float d2 = t1 - t2;
    return d2 > 0.0f ? d2 : 0.0f;
}

__device__ __forceinline__ unsigned short f2bf(float x) {
    unsigned u = __float_as_uint(x);
    unsigned r = (u + 0x7FFFu + ((u >> 16) & 1u)) >> 16;   // RTNE
    return (unsigned short)r;
}
__device__ __forceinline__ unsigned pack2(float a, float b) {
    return (unsigned)f2bf(a) | ((unsigned)f2bf(b) << 16);
}

// exact-GELU via A&S 7.1.26 erf (|eps| < 1.5e-7), branchless
__device__ __forceinline__ float gelu_fast(float v) {
    const float z  = v * 0.70710678118654752440f;
    const float az = fabsf(z);
    const float t  = __fdividef(1.0f, fmaf(0.3275911f, az, 1.0f));
    float p = fmaf(1.061405429f, t, -1.453152027f);
    p = fmaf(p, t, 1.421413741f);
    p = fmaf(p, t, -0.284496736f);
    p = fmaf(p, t, 0.254829592f);
    p = p * t;
    const float ex = __expf(-az * az);
    float erfv = fmaf(-p, ex, 1.0f);
    erfv = (z < 0.0f) ? -erfv : erfv;
    return 0.5f * v * (1.0f + erfv);
}

// ---------------------------------------------------------------------------
// Kernel 1: kNN top-16 via branch-free radix select (one wave per query).
// ---------------------------------------------------------------------------
__global__ __launch_bounds__(512) void knn_select_kernel(const float* __restrict__ coords,
                                                         int* __restrict__ knn_out) {
    __shared__ float lc[3][N_];
    __shared__ float lsq[N_];
    __shared__ int cnt[8];
    const int wave = threadIdx.x >> 6;
    const int lane = threadIdx.x & 63;
    const int p = blockIdx.x * 8 + wave;
    const int b = p >> 11;
    const int n0 = p & (N_ - 1);
    const float* cb = coords + (size_t)b * N_ * 3;
    for (int i = threadIdx.x; i < N_ * 3; i += 512) {
        int n = i / 3, c = i - 3 * n;
        lc[c][n] = cb[i];
    }
    __syncthreads();
    for (int n = threadIdx.x; n < N_; n += 512) lsq[n] = sq3_ref(lc[0][n], lc[1][n], lc[2][n]);
    __syncthreads();

    const float qx = lc[0][n0], qy = lc[1][n0], qz = lc[2][n0], sqq = lsq[n0];
    unsigned key[32];
#pragma unroll
    for (int j = 0; j < 32; ++j) {
        const int m = j * 64 + lane;
        key[j] = __float_as_uint(d2_ref(qx, qy, qz, sqq, lc[0][m], lc[1][m], lc[2][m], lsq[m]));
    }

    unsigned prefix = 0;
    int rem = K_, setc = N_, bshift = 0;
    bool bounded = false;
    for (int bit = 31; bit >= 0; --bit) {
        const unsigned want = prefix << 1;
        int c = 0;
#pragma unroll
        for (int j = 0; j < 32; ++j) c += ((key[j] >> bit) == want) ? 1 : 0;
        for (int off = 1; off < 64; off <<= 1) c += __shfl_xor(c, off, 64);
        if (rem <= c) { prefix = want; setc = c; }
        else          { prefix = want | 1u; rem -= c; setc -= c; }
        bshift = bit;
        if (setc == rem) { bounded = true; break; }
    }

    if (lane == 0) cnt[wave] = 0;
    int* op = knn_out + (size_t)p * K_;
    const unsigned long long BE = bounded ? (((unsigned long long)prefix + 1ull) << bshift)
                                          : (unsigned long long)prefix;
#pragma unroll
    for (int j = 0; j < 32; ++j) {
        if ((unsigned long long)key[j] < BE) {
            int s = atomicAdd(&cnt[wave], 1);
            op[s] = j * 64 + lane;
        }
    }
    if (!bounded) {
        const unsigned V = prefix;
#pragma unroll
        for (int j = 0; j < 32; ++j) {
            if (rem > 0) {
                unsigned long long mask = __ballot(key[j] == V);
                int below = __popcll(mask & ((1ull << lane) - 1ull));
                if (key[j] == V && below < rem) {
                    int s = atomicAdd(&cnt[wave], 1);
                    op[s] = j * 64 + lane;
                }
                rem -= __popcll(mask);
            }
        }
    }
}

// ---------------------------------------------------------------------------
// Kernel 2: prepack W1/W2/W3/Ws into bf16 MFMA A-fragments, CHUNK-MAJOR:
// chunk c (16 KiB) = fragments [16c .. 16c+15] where fragment (c,mt) holds
//   W[32*kt + 8g + i][16*mt + e],  kt = chunk-within-source, lane=(g,e).
// Chunks 0..23 = layers (L*8+kt), 24..27 = Ws (kt 0..3).  frag0 = 16*c.
// ---------------------------------------------------------------------------
__global__ __launch_bounds__(64) void wprep_kernel(const float* __restrict__ W1,
                                                   const float* __restrict__ W2,
                                                   const float* __restrict__ W3,
                                                   const float* __restrict__ Ws,
                                                   short* __restrict__ WF) {
    const int bi = blockIdx.x;          // 0..447  (= c*16 + mt)
    const int lane = threadIdx.x;
    const int g = lane >> 4, e = lane & 15;
    const float* W;
    int mt, kt;
    if (bi < 384) {
        const int L = bi >> 7;
        const int t = bi & 127;         // t = kt*16 + mt
        kt = t >> 4; mt = t & 15;
        W = (L == 0) ? W1 : (L == 1) ? W2 : W3;
    } else {
        const int t = bi - 384;
        kt = t >> 4; mt = t & 15;
        W = Ws;
    }
    const int f = 16 * mt + e;
    unsigned v[4];
#pragma unroll
    for (int i2 = 0; i2 < 4; ++i2) {
        const int k = 32 * kt + 8 * g + 2 * i2;
        v[i2] = pack2(W[(size_t)k * E_ + f], W[(size_t)(k + 1) * E_ + f]);
    }
    uint4 u; u.x = v[0]; u.y = v[1]; u.z = v[2]; u.w = v[3];
    *reinterpret_cast<uint4*>(WF + ((size_t)bi * 64 + lane) * 8) = u;
}

// ---------------------------------------------------------------------------
// Kernel 3: fused edge-MLP. One point per wave; W chunks staged in LDS via
// global_load_lds (16B), double-buffered, SHARED by the block's 4 waves.
// Pipeline per chunk: {vmcnt(0); barrier; stage(c+1 -> other buf); 16 MFMA}.
// Cross-layer chunk loads fly through the LN/GELU phase.
// acc AGPRs are REUSED for the shortcut GEMM (sel extracted first).
// ---------------------------------------------------------------------------
#define WCHUNKS 28

__device__ __forceinline__ void stage_chunk(const short* __restrict__ WF,
                                            short* __restrict__ dst,
                                            int c, int wave, int lane) {
    const short* src = WF + ((size_t)(c << 4) << 9);    // fragment 16c, *512 shorts
#pragma unroll
    for (int i = 0; i < 4; ++i) {
        const int slot = (i << 8) + (wave << 6);        // wave-uniform slot base
        const short* gp = src + ((size_t)(slot + lane) << 3);
        short* lp = dst + ((size_t)slot << 3);
        __builtin_amdgcn_global_load_lds(
            (const __attribute__((address_space(1))) void*)gp,
            (__attribute__((address_space(3))) void*)lp, 16, 0, 0);
    }
}

template <int LAST>
__device__ __forceinline__ void ln_gelu(f32x4 (&acc)[16], int e, int g,
                                        const float* __restrict__ bL,
                                        const float* __restrict__ gL,
                                        const float* __restrict__ beL,
                                        char* HB, unsigned swz) {
    float s = 0.f;
#pragma unroll
    for (int mt = 0; mt < 16; ++mt) {
        const float4 bv = *(const float4*)(bL + 16 * mt + 4 * g);
        acc[mt][0] += bv.x; acc[mt][1] += bv.y; acc[mt][2] += bv.z; acc[mt][3] += bv.w;
        s += acc[mt][0] + acc[mt][1] + acc[mt][2] + acc[mt][3];
    }
    s += __shfl_xor(s, 16, 64);
    s += __shfl_xor(s, 32, 64);
    const float mu = s * (1.0f / 256.0f);
    float q = 0.f;
#pragma unroll
    for (int mt = 0; mt < 16; ++mt) {
#pragma unroll
        for (int i = 0; i < 4; ++i) { const float d = acc[mt][i] - mu; q = fmaf(d, d, q); }
    }
    q += __shfl_xor(q, 16, 64);
    q += __shfl_xor(q, 32, 64);
    const float rstd = rsqrtf(q * (1.0f / 256.0f) + LN_EPS);
#pragma unroll
    for (int mt = 0; mt < 16; ++mt) {
        const float4 gv  = *(const float4*)(gL + 16 * mt + 4 * g);
        const float4 bev = *(const float4*)(beL + 16 * mt + 4 * g);
        const float r0 = gelu_fast(fmaf((acc[mt][0] - mu) * rstd, gv.x, bev.x));
        const float r1 = gelu_fast(fmaf((acc[mt][1] - mu) * rstd, gv.y, bev.y));
        const float r2 = gelu_fast(fmaf((acc[mt][2] - mu) * rstd, gv.z, bev.z));
        const float r3 = gelu_fast(fmaf((acc[mt][3] - mu) * rstd, gv.w, bev.w));
        if (LAST) {
            acc[mt][0] = r0; acc[mt][1] = r1; acc[mt][2] = r2; acc[mt][3] = r3;
        } else {
            *(uint2*)(HB + (((e << 9) + (mt << 5) + (g << 3)) ^ swz)) =
                make_uint2(pack2(r0, r1), pack2(r2, r3));
        }
    }
}

__global__ __launch_bounds__(256, 2) void edgeconv_mfma(
    const float* __restrict__ x, const int* __restrict__ knn,
    const short* __restrict__ WF,
    const float* __restrict__ b1, const float* __restrict__ g1, const float* __restrict__ be1,
    const float* __restrict__ b2, const float* __restrict__ g2, const float* __restrict__ be2,
    const float* __restrict__ b3, const float* __restrict__ g3, const float* __restrict__ be3,
    const float* __restrict__ bs,
    float* __restrict__ out)
{
    __shared__ short Hl[4][4096];       // 32 KiB: 4 waves x (16x256 bf16), XOR-swizzled
    __shared__ short Wbuf[2][8192];     // 32 KiB: double-buffered 16 KiB W chunks
    __shared__ short Hx[4][128];        // 1 KiB: broadcast bf16 x-row per wave
    const int tid  = threadIdx.x;
    const int wave = tid >> 6;
    const int lane = tid & 63;
    const int e = lane & 15;
    const int g = lane >> 4;
    const int p = blockIdx.x * 4 + wave;
    const int b = p >> 11;
    const int n = p & (N_ - 1);
    const unsigned swz = (unsigned)((e & 7) << 4);
    char* H0 = (char*)&Hl[wave][0];
    char* XC = (char*)&Hx[wave][0];

    // issue chunk-0 staging first so it flies under the H build
    stage_chunk(WF, &Wbuf[0][0], 0, wave, lane);

    // ---- edge build: H[e][0:128]=central, H[e][128:256]=nbr-central
    {
        const float4* xr = (const float4*)(x + ((size_t)b * N_ + n) * D_);
        const int nb = knn[(size_t)p * K_ + e];
        const float4* nr = (const float4*)(x + ((size_t)b * N_ + nb) * D_);
#pragma unroll
        for (int c2 = 0; c2 < 8; ++c2) {
            const float4 cv = xr[8 * g + c2];
            const float4 nv = nr[8 * g + c2];
            const int base = (e << 9) + (g << 6) + (c2 << 3);
            const uint2 cpk = make_uint2(pack2(cv.x, cv.y), pack2(cv.z, cv.w));
            *(uint2*)(H0 + (base ^ swz)) = cpk;
            *(uint2*)(H0 + ((base + 256) ^ swz)) =
                make_uint2(pack2(nv.x - cv.x, nv.y - cv.y), pack2(nv.z - cv.z, nv.w - cv.w));
            if (e == 0) *(uint2*)(XC + (g << 6) + (c2 << 3)) = cpk;
        }
    }

    f32x4 acc[16];
    int pb = 0;                                      // current W buffer parity
    const f32x4 z = {0.f, 0.f, 0.f, 0.f};

    for (int L = 0; L < 3; ++L) {
        const float* bL  = (L == 0) ? b1  : (L == 1) ? b2  : b3;
        const float* gL  = (L == 0) ? g1  : (L == 1) ? g2  : g3;
        const float* beL = (L == 0) ? be1 : (L == 1) ? be2 : be3;

#pragma unroll
        for (int mt = 0; mt < 16; ++mt) acc[mt] = z;

        for (int kt = 0; kt < 8; ++kt) {
            const int c = L * 8 + kt;
            asm volatile("s_waitcnt vmcnt(0)" ::: "memory");   // our stage loads of c done
            __syncthreads();                                    // c visible; prev buf free
            if (c + 1 < WCHUNKS) stage_chunk(WF, &Wbuf[pb ^ 1][0], c + 1, wave, lane);
            const bf16x8 Bc = *(const bf16x8*)(H0 + (((e << 9) + (kt << 6) + (g << 4)) ^ swz));
            const short* Wc = &Wbuf[pb][0];
#pragma unroll
            for (int mt = 0; mt < 16; ++mt) {
                const bf16x8 a = *(const bf16x8*)(Wc + (((mt << 6) + lane) << 3));
                acc[mt] = __builtin_amdgcn_mfma_f32_16x16x32_bf16(a, Bc, acc[mt], 0, 0, 0);
            }
            pb ^= 1;
        }

        if (L < 2) {
            ln_gelu<0>(acc, e, g, bL, gL, beL, H0, swz);
            asm volatile("s_waitcnt lgkmcnt(0)" ::: "memory");
        } else {
            ln_gelu<1>(acc, e, g, bL, gL, beL, H0, swz);
        }
    }

    // ---- max over 16 edges (reduce across e-lanes) + select own tile ----
#pragma unroll
    for (int mt = 0; mt < 16; ++mt) {
#pragma unroll
        for (int i = 0; i < 4; ++i) {
            float v0 = acc[mt][i];
#pragma unroll
            for (int off = 1; off < 16; off <<= 1) v0 = fmaxf(v0, __shfl_xor(v0, off, 64));
            acc[mt][i] = v0;
        }
    }
    f32x4 sel = acc[0];
#pragma unroll
    for (int mt = 1; mt < 16; ++mt) {
        if (e == mt) sel = acc[mt];
    }

    // ---- shortcut x @ Ws via MFMA (chunks 24..27), REUSING acc ----
#pragma unroll
    for (int mt = 0; mt < 16; ++mt) acc[mt] = z;
    for (int kt = 0; kt < 4; ++kt) {
        const int c = 24 + kt;
        asm volatile("s_waitcnt vmcnt(0)" ::: "memory");
        __syncthreads();
        if (c + 1 < WCHUNKS) stage_chunk(WF, &Wbuf[pb ^ 1][0], c + 1, wave, lane);
        const bf16x8 bx = *(const bf16x8*)(XC + (kt << 6) + (g << 4));
        const short* Wc = &Wbuf[pb][0];
#pragma unroll
        for (int mt = 0; mt < 16; ++mt) {
            const bf16x8 a = *(const bf16x8*)(Wc + (((mt << 6) + lane) << 3));
            acc[mt] = __builtin_amdgcn_mfma_f32_16x16x32_bf16(a, bx, acc[mt], 0, 0, 0);
        }
        pb ^= 1;
    }
    f32x4 ssc = acc[0];
#pragma unroll
    for (int mt = 1; mt < 16; ++mt) {
        if (e == mt) ssc = acc[mt];
    }

    const int f0 = 16 * e + 4 * g;
    const float4 bsv = *(const float4*)(bs + f0);
    float4 o;
    o.x = gelu_fast(sel[0] + ssc[0] + bsv.x);
    o.y = gelu_fast(sel[1] + ssc[1] + bsv.y);
    o.z = gelu_fast(sel[2] + ssc[2] + bsv.z);
    o.w = gelu_fast(sel[3] + ssc[3] + bsv.w);
    *(float4*)(out + (size_t)p * E_ + f0) = o;
}

extern "C" void kernel_launch(void* const* d_in, const int* in_sizes, int n_in,
                              void* d_out, int out_size, void* d_ws, size_t ws_size,
                              hipStream_t stream) {
    const float* x      = (const float*)d_in[0];
    const float* coords = (const float*)d_in[1];
    const float* W1  = (const float*)d_in[2];
    const float* b1  = (const float*)d_in[3];
    const float* g1  = (const float*)d_in[4];
    const float* be1 = (const float*)d_in[5];
    const float* W2  = (const float*)d_in[6];
    const float* b2  = (const float*)d_in[7];
    const float* g2  = (const float*)d_in[8];
    const float* be2 = (const float*)d_in[9];
    const float* W3  = (const float*)d_in[10];
    const float* b3  = (const float*)d_in[11];
    const float* g3  = (const float*)d_in[12];
    const float* be3 = (const float*)d_in[13];
    const float* Ws  = (const float*)d_in[14];
    const float* bs  = (const float*)d_in[15];
    float* out = (float*)d_out;

    int*   knn = (int*)d_ws;                          // 1 MiB
    short* WF  = (short*)((char*)d_ws + (1 << 20));   // 448 KiB bf16 fragments

    wprep_kernel<<<448, 64, 0, stream>>>(W1, W2, W3, Ws, WF);
    knn_select_kernel<<<B_ * (N_ / 8), 512, 0, stream>>>(coords, knn);
    edgeconv_mfma<<<(B_ * N_) / 4, 256, 0, stream>>>(
        x, knn, WF, b1, g1, be1, b2, g2, be2, b3, g3, be3, bs, out);
}